// Round 6
// baseline (367.304 us; speedup 1.0000x reference)
//
#include <hip/hip_runtime.h>

// Problem constants: B=2, T=2048, P=2048, C=1024, H=16, HD=64, S=P+T=4096
#define BB 2
#define TT 2048
#define PP 2048
#define CC 1024
#define HH 16
#define SS 4096

typedef unsigned short u16;
typedef __attribute__((ext_vector_type(8))) short s16x8;
typedef __attribute__((ext_vector_type(4))) float f32x4;
typedef __attribute__((ext_vector_type(4))) unsigned short u16x4;

// fold 1/sqrt(HD)=0.125 and log2(e) into q so softmax uses exp2 directly
#define QSCALE 0.18033688011112042f

__device__ __forceinline__ u16 f2bf(float f) {
  unsigned u = __float_as_uint(f);
  u += 0x7fff + ((u >> 16) & 1);   // RNE
  return (u16)(u >> 16);
}

// cheap round-half-up bf16 for P (positive values; ties-vs-RNE diff << threshold headroom)
__device__ __forceinline__ u16 p2bf(float f) {
  return (u16)((__float_as_uint(f) + 0x8000u) >> 16);
}

// ---------------- elementwise fp32 -> bf16 (x) ----------------
__global__ __launch_bounds__(256) void cvt_f32_bf16(const float* __restrict__ src,
                                                    u16* __restrict__ dst) {
  size_t i = ((size_t)blockIdx.x * 256 + threadIdx.x) * 4;
  f32x4 v = *(const f32x4*)(src + i);
  u16x4 o = { f2bf(v[0]), f2bf(v[1]), f2bf(v[2]), f2bf(v[3]) };
  *(u16x4*)(dst + i) = o;
}

// ---------------- transpose + convert: dst[c][r] = bf16(src[r][c]) ----------------
__global__ __launch_bounds__(256) void transpose_w_bf16(const float* __restrict__ src,
                                                        u16* __restrict__ dst,
                                                        int rows, int cols) {
  __shared__ float tile[64][65];
  int r0 = blockIdx.y * 64, c0 = blockIdx.x * 64;
  int tx = threadIdx.x & 63, ty = threadIdx.x >> 6;
#pragma unroll
  for (int i = 0; i < 16; i++) {
    int r = ty + i * 4;
    tile[r][tx] = src[(size_t)(r0 + r) * cols + c0 + tx];
  }
  __syncthreads();
#pragma unroll
  for (int i = 0; i < 16; i++) {
    int cc = ty + i * 4;
    dst[(size_t)(c0 + cc) * rows + r0 + tx] = f2bf(tile[tx][cc]);
  }
}

// ---------------- cache copy: fp32 passthrough + k bf16 ----------------
__global__ __launch_bounds__(256) void cache_copy(const float* __restrict__ kc,
                                                  const float* __restrict__ vc,
                                                  float* __restrict__ kf,
                                                  float* __restrict__ vf,
                                                  u16* __restrict__ kb) {
  size_t flat = ((size_t)blockIdx.x * 256 + threadIdx.x) * 4;  // over B*P*C
  int b = (int)(flat >> 21);                   // / (P*C)
  size_t dsto = flat + (size_t)b * (TT * CC);  // insert gap of T rows per batch
  f32x4 kv = *(const f32x4*)(kc + flat);
  f32x4 vv = *(const f32x4*)(vc + flat);
  *(f32x4*)(kf + dsto) = kv;
  *(f32x4*)(vf + dsto) = vv;
  u16x4 k4 = { f2bf(kv[0]), f2bf(kv[1]), f2bf(kv[2]), f2bf(kv[3]) };
  *(u16x4*)(kb + dsto) = k4;
}

// ---------------- v_cache -> vT bf16 [B,H,HD,S] (tiled transpose) ----------------
__global__ __launch_bounds__(256) void vT_cache_kernel(const float* __restrict__ vc,
                                                       u16* __restrict__ vTb) {
  __shared__ float tile[64][65];
  int bh = blockIdx.y, b = bh >> 4, h = bh & 15;
  int p0 = blockIdx.x * 64;
  int tx = threadIdx.x & 63, ty = threadIdx.x >> 6;
#pragma unroll
  for (int i = 0; i < 16; i++) {
    int p = ty + i * 4;
    tile[p][tx] = vc[(size_t)(b * PP + p0 + p) * CC + h * 64 + tx];
  }
  __syncthreads();
#pragma unroll
  for (int i = 0; i < 16; i++) {
    int d = ty + i * 4;
    vTb[(size_t)((b * HH + h) * 64 + d) * SS + p0 + tx] = f2bf(tile[tx][d]);
  }
}

// ---------------- v_rem (fp32 rows PP.. of out_v) -> vT bf16 ----------------
__global__ __launch_bounds__(256) void vT_rem_kernel(const float* __restrict__ vf,
                                                     u16* __restrict__ vTb) {
  __shared__ float tile[64][65];
  int bh = blockIdx.y, b = bh >> 4, h = bh & 15;
  int p0 = blockIdx.x * 64;  // within T
  int tx = threadIdx.x & 63, ty = threadIdx.x >> 6;
#pragma unroll
  for (int i = 0; i < 16; i++) {
    int p = ty + i * 4;
    tile[p][tx] = vf[(size_t)(b * SS + PP + p0 + p) * CC + h * 64 + tx];
  }
  __syncthreads();
#pragma unroll
  for (int i = 0; i < 16; i++) {
    int d = ty + i * 4;
    vTb[(size_t)((b * HH + h) * 64 + d) * SS + PP + p0 + tx] = f2bf(tile[tx][d]);
  }
}

// ---------------- GEMM: C[MxN] = A[Mx1024] * BT[Nx1024]^T (bf16 MFMA) ----------------
// mode 0: plain fp32 out (ld = N). mode 1: qkv routing epilogue.
__global__ __launch_bounds__(256) void gemm_bt(const u16* __restrict__ A,
                                               const u16* __restrict__ BT,
                                               int N, int mode,
                                               float* __restrict__ out0,
                                               u16* __restrict__ qb,
                                               float* __restrict__ kf,
                                               u16* __restrict__ kb,
                                               float* __restrict__ vf) {
  __shared__ u16 As[128 * 72];
  __shared__ u16 Bs[128 * 72];
  const int m0 = blockIdx.y * 128, n0 = blockIdx.x * 128;
  const int tid = threadIdx.x, lane = tid & 63, wave = tid >> 6;
  const int wm = wave & 1, wn = wave >> 1;
  const int c = lane & 15, quad = lane >> 4;
  const int chunk = tid & 7, rp = tid >> 3;

  f32x4 acc[4][4] = {};

  for (int k0 = 0; k0 < 1024; k0 += 64) {
#pragma unroll
    for (int it = 0; it < 4; it++) {
      int r = it * 32 + rp;
      *(s16x8*)&As[r * 72 + chunk * 8] =
          *(const s16x8*)(A + (size_t)(m0 + r) * 1024 + k0 + chunk * 8);
      *(s16x8*)&Bs[r * 72 + chunk * 8] =
          *(const s16x8*)(BT + (size_t)(n0 + r) * 1024 + k0 + chunk * 8);
    }
    __syncthreads();
#pragma unroll
    for (int kc = 0; kc < 64; kc += 32) {
      s16x8 af[4], bf[4];
#pragma unroll
      for (int i = 0; i < 4; i++) {
        af[i] = *(const s16x8*)&As[(wm * 64 + i * 16 + c) * 72 + kc + quad * 8];
        bf[i] = *(const s16x8*)&Bs[(wn * 64 + i * 16 + c) * 72 + kc + quad * 8];
      }
#pragma unroll
      for (int mi = 0; mi < 4; mi++)
#pragma unroll
        for (int ni = 0; ni < 4; ni++)
          acc[mi][ni] = __builtin_amdgcn_mfma_f32_16x16x32_bf16(af[mi], bf[ni], acc[mi][ni], 0, 0, 0);
    }
    __syncthreads();
  }

  // epilogue: C[row = m0+wm*64+mi*16+quad*4+reg][col = n0+wn*64+ni*16+c]
#pragma unroll
  for (int mi = 0; mi < 4; mi++) {
#pragma unroll
    for (int ni = 0; ni < 4; ni++) {
      f32x4 v = acc[mi][ni];
      int gmb = m0 + wm * 64 + mi * 16 + quad * 4;
      int gn = n0 + wn * 64 + ni * 16 + c;
      if (mode == 0) {
#pragma unroll
        for (int r = 0; r < 4; r++)
          out0[(size_t)(gmb + r) * N + gn] = v[r];
      } else {
        int region = n0 >> 10;  // whole block-column lies in one region
        if (region == 0) {
#pragma unroll
          for (int r = 0; r < 4; r++)
            qb[(size_t)(gmb + r) * 1024 + gn] = f2bf(v[r] * QSCALE);
        } else if (region == 1) {
          int ccol = gn - 1024;
#pragma unroll
          for (int r = 0; r < 4; r++) {
            int gm = gmb + r, b = gm >> 11, t = gm & 2047;
            size_t off = (size_t)b * (SS * CC) + (size_t)(PP + t) * CC + ccol;
            kf[off] = v[r];
            kb[off] = f2bf(v[r]);
          }
        } else {
          int ccol = gn - 2048;
#pragma unroll
          for (int r = 0; r < 4; r++) {
            int gm = gmb + r, b = gm >> 11, t = gm & 2047;
            vf[(size_t)b * (SS * CC) + (size_t)(PP + t) * CC + ccol] = v[r];
          }
        }
      }
    }
  }
}

// ---------------- flash attention v9 ----------------
// LDS-pipe-bound fix: 4 waves x 2x16-row strips (r1-verified indices) so K/V frag reads
// amortize over 2x MFMA work; Ps -> unpadded [32][64] + XOR swizzle (write ^quad<<4,
// read ^(c>>2)<<4) = conflict-free both sides and 53KB LDS -> 3 blocks/CU.
// Keeps all v8 wins: dbuf 1-barrier/iter, reg ones, rare-max branch, p2bf, stage-late,
// setprio, XCD-pinned grid.
__global__ __launch_bounds__(256, 3) void attn_kernel(const u16* __restrict__ qb,
                                                      const u16* __restrict__ kb,
                                                      const u16* __restrict__ vT,
                                                      u16* __restrict__ yb) {
  __shared__ u16 Ks[2][64 * 72];
  __shared__ u16 Vs[2][64 * 72];
  __shared__ u16 Ps[4][32 * 64];
  // XCD-pinned mapping (r3-verified bijection): XCD x owns bh 4x..4x+3; heavy q-tiles first
  const int L = blockIdx.x;
  const int xcd = L & 7, rest = L >> 3;
  const int qt = 15 - (rest >> 2);
  const int bh = (xcd << 2) | (rest & 3);
  const int b = bh >> 4, h = bh & 15;
  const int q0 = qt * 128;
  const int tid = threadIdx.x, lane = tid & 63, wave = tid >> 6;
  const int c = lane & 15, quad = lane >> 4;
  const int chunk = tid & 7, rp = tid >> 3;   // 256 threads: 32 rows x 8 chunks

  const int s_end = PP + q0 + 128;

  // staging pointers: each thread loads rows rp and rp+32 of the 64-row K/V tile
  const u16* kptr = kb + (size_t)(b * SS + rp) * 1024 + h * 64 + chunk * 8;
  const u16* vptr = vT + (size_t)((b * HH + h) * 64 + rp) * SS + chunk * 8;

  // prologue: tile 0 -> buffer 0 (published by the first in-loop barrier)
  {
    s16x8 k0 = *(const s16x8*)kptr;
    s16x8 k1 = *(const s16x8*)(kptr + 32 * 1024);
    s16x8 v0 = *(const s16x8*)vptr;
    s16x8 v1 = *(const s16x8*)(vptr + (size_t)32 * SS);
    *(s16x8*)&Ks[0][rp * 72 + chunk * 8] = k0;
    *(s16x8*)&Ks[0][(rp + 32) * 72 + chunk * 8] = k1;
    *(s16x8*)&Vs[0][rp * 72 + chunk * 8] = v0;
    *(s16x8*)&Vs[0][(rp + 32) * 72 + chunk * 8] = v1;
  }

  // ones B-operand in registers: B[k][n=c] = 1 iff c==0 (row-sum column)
  const short ov = (c == 0) ? (short)0x3F80 : (short)0;
  const s16x8 ones = { ov, ov, ov, ov, ov, ov, ov, ov };

  // Q fragments (A-layout): strip st owns rows q0 + wave*32 + st*16 + (0..15)
  s16x8 qf[2][2];
#pragma unroll
  for (int st = 0; st < 2; st++) {
    int qr = q0 + wave * 32 + st * 16 + c;
    qf[st][0] = *(const s16x8*)(qb + (size_t)(b * TT + qr) * 1024 + h * 64 + quad * 8);
    qf[st][1] = *(const s16x8*)(qb + (size_t)(b * TT + qr) * 1024 + h * 64 + 32 + quad * 8);
  }

  f32x4 o[2][5] = {};   // per strip: [0..3] output d-tiles, [4] row-sum
  float m = -1e30f;     // wave-scalar running max (upper bound for all 32 rows)
  u16* Pw = Ps[wave];
  s16x8 kr0, kr1, vr0, vr1;

  int cur = 0;
  for (int s0 = 0; s0 < s_end; s0 += 64, cur ^= 1) {
    __syncthreads();   // publish tile s0 writes; all waves done reading buffer cur^1

    const bool more = (s0 + 64 < s_end);
    if (more) {        // issue next-tile loads; consumed at the stage section below
      kptr += 64 * 1024;
      vptr += 64;
      kr0 = *(const s16x8*)kptr;
      kr1 = *(const s16x8*)(kptr + 32 * 1024);
      vr0 = *(const s16x8*)vptr;
      vr1 = *(const s16x8*)(vptr + (size_t)32 * SS);
    }

    const u16* Kc = Ks[cur];
    const u16* Vc = Vs[cur];

    // scores: K frags read once, shared by both strips
    f32x4 sc[2][4];
    __builtin_amdgcn_s_setprio(1);
#pragma unroll
    for (int nt = 0; nt < 4; nt++) {
      s16x8 kf0 = *(const s16x8*)&Kc[(nt * 16 + c) * 72 + quad * 8];
      s16x8 kf1 = *(const s16x8*)&Kc[(nt * 16 + c) * 72 + 32 + quad * 8];
#pragma unroll
      for (int st = 0; st < 2; st++) {
        f32x4 z = { 0.f, 0.f, 0.f, 0.f };
        z = __builtin_amdgcn_mfma_f32_16x16x32_bf16(qf[st][0], kf0, z, 0, 0, 0);
        z = __builtin_amdgcn_mfma_f32_16x16x32_bf16(qf[st][1], kf1, z, 0, 0, 0);
        sc[st][nt] = z;
      }
    }
    __builtin_amdgcn_s_setprio(0);

    // first-half V-frags hoisted: LDS latency hides under mask/softmax VALU below
    s16x8 vf0[4];
#pragma unroll
    for (int dt = 0; dt < 4; dt++)
      vf0[dt] = *(const s16x8*)&Vc[(dt * 16 + c) * 72 + quad * 8];

    const int diag = s0 - (PP + q0);
    if (diag >= 0) {  // causal mask (block diagonal region spans 2 tiles)
#pragma unroll
      for (int st = 0; st < 2; st++)
#pragma unroll
        for (int nt = 0; nt < 4; nt++) {
          int col = nt * 16 + c + diag;
#pragma unroll
          for (int r = 0; r < 4; r++) {
            int rq = wave * 32 + st * 16 + quad * 4 + r;
            if (col > rq) sc[st][nt][r] = -1e30f;
          }
        }
    }

    // defer-max: shuffle-free common path (wave max > m+8 <=> some lane's lm > m+8)
    float lm = -1e30f;
#pragma unroll
    for (int st = 0; st < 2; st++)
#pragma unroll
      for (int nt = 0; nt < 4; nt++)
        lm = fmaxf(lm, fmaxf(fmaxf(sc[st][nt][0], sc[st][nt][1]),
                             fmaxf(sc[st][nt][2], sc[st][nt][3])));
    if (__any(lm > m + 8.0f)) {            // rare (~once per block)
#pragma unroll
      for (int off = 1; off < 64; off <<= 1)
        lm = fmaxf(lm, __shfl_xor(lm, off, 64));
      float alpha = __builtin_amdgcn_exp2f(m - lm);
      m = lm;
#pragma unroll
      for (int st = 0; st < 2; st++)
#pragma unroll
        for (int dt = 0; dt < 5; dt++)
#pragma unroll
          for (int r = 0; r < 4; r++) o[st][dt][r] *= alpha;
    }

    // p = exp2(sc - m) -> bf16 (2-op round) -> Ps[32][64] with XOR swizzle:
    // write idx ^= quad<<4 (row bits -> 16B-granule), read idx ^= (c>>2)<<4.
    // Per-row key is the same on both sides (row>>2 & 3 == quad on write, c>>2 on read),
    // writes hit all 32 banks (conflict-free), reads stay 8-lane-per-slot minimum.
#pragma unroll
    for (int st = 0; st < 2; st++)
#pragma unroll
      for (int nt = 0; nt < 4; nt++)
#pragma unroll
        for (int r = 0; r < 4; r++)
          Pw[(((st * 16 + quad * 4 + r) << 6) + nt * 16 + c) ^ (quad << 4)] =
              p2bf(__builtin_amdgcn_exp2f(sc[st][nt][r] - m));
    s16x8 pa[2][2];
#pragma unroll
    for (int st = 0; st < 2; st++) {
      int base = (st * 16 + c) << 6;
      int key = (c >> 2) << 4;
      pa[st][0] = *(const s16x8*)&Pw[(base + quad * 8) ^ key];
      pa[st][1] = *(const s16x8*)&Pw[(base + 32 + quad * 8) ^ key];
    }

    // stage tile i+1 into the OTHER buffer now; ds_write latency hides under PV MFMAs
    // (safe: buffer cur^1 is dead after the top barrier of this iteration)
    if (more) {
      *(s16x8*)&Ks[cur ^ 1][rp * 72 + chunk * 8] = kr0;
      *(s16x8*)&Ks[cur ^ 1][(rp + 32) * 72 + chunk * 8] = kr1;
      *(s16x8*)&Vs[cur ^ 1][rp * 72 + chunk * 8] = vr0;
      *(s16x8*)&Vs[cur ^ 1][(rp + 32) * 72 + chunk * 8] = vr1;
    }

    // PV: V frags shared by both strips (second half read inline)
    __builtin_amdgcn_s_setprio(1);
#pragma unroll
    for (int dt = 0; dt < 4; dt++) {
      s16x8 vb1 = *(const s16x8*)&Vc[(dt * 16 + c) * 72 + 32 + quad * 8];
#pragma unroll
      for (int st = 0; st < 2; st++) {
        o[st][dt] = __builtin_amdgcn_mfma_f32_16x16x32_bf16(pa[st][0], vf0[dt], o[st][dt], 0, 0, 0);
        o[st][dt] = __builtin_amdgcn_mfma_f32_16x16x32_bf16(pa[st][1], vb1, o[st][dt], 0, 0, 0);
      }
    }
#pragma unroll
    for (int st = 0; st < 2; st++) {
      o[st][4] = __builtin_amdgcn_mfma_f32_16x16x32_bf16(pa[st][0], ones, o[st][4], 0, 0, 0);
      o[st][4] = __builtin_amdgcn_mfma_f32_16x16x32_bf16(pa[st][1], ones, o[st][4], 0, 0, 0);
    }
    __builtin_amdgcn_s_setprio(0);
  }

  // normalize: l for q-row (quad*4+r) lives in o[st][4][r] at lane c==0 of each quad
#pragma unroll
  for (int st = 0; st < 2; st++)
#pragma unroll
    for (int r = 0; r < 4; r++) {
      float l = __shfl(o[st][4][r], (lane & 48), 64);
      float inv = 1.0f / l;
      int qr = q0 + wave * 32 + st * 16 + quad * 4 + r;
#pragma unroll
      for (int dt = 0; dt < 4; dt++)
        yb[(size_t)(b * TT + qr) * 1024 + h * 64 + dt * 16 + c] = f2bf(o[st][dt][r] * inv);
    }
}

extern "C" void kernel_launch(void* const* d_in, const int* in_sizes, int n_in,
                              void* d_out, int out_size, void* d_ws, size_t ws_size,
                              hipStream_t stream) {
  const float* x       = (const float*)d_in[0];
  const float* k_cache = (const float*)d_in[1];
  const float* v_cache = (const float*)d_in[2];
  const float* W_attn  = (const float*)d_in[3];
  const float* W_proj  = (const float*)d_in[4];

  float* out_y = (float*)d_out;                       // [B,T,C]   4,194,304
  float* out_k = out_y + (size_t)BB * TT * CC;        // [B,S,C]   8,388,608
  float* out_v = out_k + (size_t)BB * SS * CC;        // [B,S,C]   8,388,608

  u16* xb  = (u16*)d_ws;                 // 4,194,304  x bf16
  u16* WaT = xb  + 4194304;              // 3,145,728  W_attn^T bf16 [3072,1024]
  u16* WpT = WaT + 3145728;              // 1,048,576  W_proj^T bf16 [1024,1024]
  u16* qb  = WpT + 1048576;              // 4,194,304  q bf16 (scaled) [B*T,1024]
  u16* kb  = qb  + 4194304;              // 8,388,608  k bf16 [B,S,C]
  u16* vT  = kb  + 8388608;              // 8,388,608  v^T bf16 [B,H,64,S]
  u16* yb  = vT  + 8388608;              // 4,194,304  attn out bf16 [B*T,1024]

  cvt_f32_bf16<<<dim3(4096), dim3(256), 0, stream>>>(x, xb);
  transpose_w_bf16<<<dim3(48, 16), dim3(256), 0, stream>>>(W_attn, WaT, 1024, 3072);
  transpose_w_bf16<<<dim3(16, 16), dim3(256), 0, stream>>>(W_proj, WpT, 1024, 1024);
  cache_copy<<<dim3(4096), dim3(256), 0, stream>>>(k_cache, v_cache, out_k, out_v, kb);
  vT_cache_kernel<<<dim3(32, 32), dim3(256), 0, stream>>>(v_cache, vT);
  gemm_bt<<<dim3(24, 32), dim3(256), 0, stream>>>(xb, WaT, 3072, 1, nullptr, qb, out_k, kb, out_v);
  vT_rem_kernel<<<dim3(32, 32), dim3(256), 0, stream>>>(out_v, vT);
  attn_kernel<<<dim3(512), dim3(256), 0, stream>>>(qb, kb, vT, yb);
  gemm_bt<<<dim3(8, 32), dim3(256), 0, stream>>>(yb, WpT, 1024, 0, out_y, nullptr, nullptr, nullptr, nullptr);
}

// Round 7
// 316.745 us; speedup vs baseline: 1.1596x; 1.1596x over previous
//
#include <hip/hip_runtime.h>

// Problem constants: B=2, T=2048, P=2048, C=1024, H=16, HD=64, S=P+T=4096
#define BB 2
#define TT 2048
#define PP 2048
#define CC 1024
#define HH 16
#define SS 4096

typedef unsigned short u16;
typedef unsigned int u32;
typedef __attribute__((ext_vector_type(8))) short s16x8;
typedef __attribute__((ext_vector_type(4))) float f32x4;
typedef __attribute__((ext_vector_type(4))) unsigned short u16x4;

// async global->LDS DMA, 16B per lane: LDS dest = uniform base + lane*16
#define GLOAD16(g, l)                                                                   \
  __builtin_amdgcn_global_load_lds((const __attribute__((address_space(1))) u32*)(g),   \
                                   (__attribute__((address_space(3))) u32*)(l), 16, 0, 0)

// fold 1/sqrt(HD)=0.125 and log2(e) into q so softmax uses exp2 directly
#define QSCALE 0.18033688011112042f

__device__ __forceinline__ u16 f2bf(float f) {
  unsigned u = __float_as_uint(f);
  u += 0x7fff + ((u >> 16) & 1);   // RNE
  return (u16)(u >> 16);
}

// cheap round-half-up bf16 for P (positive values; ties-vs-RNE diff << threshold headroom)
__device__ __forceinline__ u16 p2bf(float f) {
  return (u16)((__float_as_uint(f) + 0x8000u) >> 16);
}

// ---------------- elementwise fp32 -> bf16 (x) ----------------
__global__ __launch_bounds__(256) void cvt_f32_bf16(const float* __restrict__ src,
                                                    u16* __restrict__ dst) {
  size_t i = ((size_t)blockIdx.x * 256 + threadIdx.x) * 4;
  f32x4 v = *(const f32x4*)(src + i);
  u16x4 o = { f2bf(v[0]), f2bf(v[1]), f2bf(v[2]), f2bf(v[3]) };
  *(u16x4*)(dst + i) = o;
}

// ---------------- transpose + convert: dst[c][r] = bf16(src[r][c]) ----------------
__global__ __launch_bounds__(256) void transpose_w_bf16(const float* __restrict__ src,
                                                        u16* __restrict__ dst,
                                                        int rows, int cols) {
  __shared__ float tile[64][65];
  int r0 = blockIdx.y * 64, c0 = blockIdx.x * 64;
  int tx = threadIdx.x & 63, ty = threadIdx.x >> 6;
#pragma unroll
  for (int i = 0; i < 16; i++) {
    int r = ty + i * 4;
    tile[r][tx] = src[(size_t)(r0 + r) * cols + c0 + tx];
  }
  __syncthreads();
#pragma unroll
  for (int i = 0; i < 16; i++) {
    int cc = ty + i * 4;
    dst[(size_t)(c0 + cc) * rows + r0 + tx] = f2bf(tile[tx][cc]);
  }
}

// ---------------- cache copy: fp32 passthrough + k bf16 ----------------
__global__ __launch_bounds__(256) void cache_copy(const float* __restrict__ kc,
                                                  const float* __restrict__ vc,
                                                  float* __restrict__ kf,
                                                  float* __restrict__ vf,
                                                  u16* __restrict__ kb) {
  size_t flat = ((size_t)blockIdx.x * 256 + threadIdx.x) * 4;  // over B*P*C
  int b = (int)(flat >> 21);                   // / (P*C)
  size_t dsto = flat + (size_t)b * (TT * CC);  // insert gap of T rows per batch
  f32x4 kv = *(const f32x4*)(kc + flat);
  f32x4 vv = *(const f32x4*)(vc + flat);
  *(f32x4*)(kf + dsto) = kv;
  *(f32x4*)(vf + dsto) = vv;
  u16x4 k4 = { f2bf(kv[0]), f2bf(kv[1]), f2bf(kv[2]), f2bf(kv[3]) };
  *(u16x4*)(kb + dsto) = k4;
}

// ---------------- v_cache -> vT bf16 [B,H,HD,S] (tiled transpose) ----------------
__global__ __launch_bounds__(256) void vT_cache_kernel(const float* __restrict__ vc,
                                                       u16* __restrict__ vTb) {
  __shared__ float tile[64][65];
  int bh = blockIdx.y, b = bh >> 4, h = bh & 15;
  int p0 = blockIdx.x * 64;
  int tx = threadIdx.x & 63, ty = threadIdx.x >> 6;
#pragma unroll
  for (int i = 0; i < 16; i++) {
    int p = ty + i * 4;
    tile[p][tx] = vc[(size_t)(b * PP + p0 + p) * CC + h * 64 + tx];
  }
  __syncthreads();
#pragma unroll
  for (int i = 0; i < 16; i++) {
    int d = ty + i * 4;
    vTb[(size_t)((b * HH + h) * 64 + d) * SS + p0 + tx] = f2bf(tile[tx][d]);
  }
}

// ---------------- v_rem (fp32 rows PP.. of out_v) -> vT bf16 ----------------
__global__ __launch_bounds__(256) void vT_rem_kernel(const float* __restrict__ vf,
                                                     u16* __restrict__ vTb) {
  __shared__ float tile[64][65];
  int bh = blockIdx.y, b = bh >> 4, h = bh & 15;
  int p0 = blockIdx.x * 64;  // within T
  int tx = threadIdx.x & 63, ty = threadIdx.x >> 6;
#pragma unroll
  for (int i = 0; i < 16; i++) {
    int p = ty + i * 4;
    tile[p][tx] = vf[(size_t)(b * SS + PP + p0 + p) * CC + h * 64 + tx];
  }
  __syncthreads();
#pragma unroll
  for (int i = 0; i < 16; i++) {
    int d = ty + i * 4;
    vTb[(size_t)((b * HH + h) * 64 + d) * SS + PP + p0 + tx] = f2bf(tile[tx][d]);
  }
}

// ---------------- GEMM: C[MxN] = A[Mx1024] * BT[Nx1024]^T (bf16 MFMA) ----------------
// m97-style staging: global_load_lds width-16 into LINEAR [128][64] LDS, source-swizzled
// (scol = (lane&7)^(srow&7)) so reads XOR (row&7)<<3 are bank-uniform (rule-21 T2).
// mode 0: plain fp32 out (ld = N). mode 1: qkv routing epilogue.
__global__ __launch_bounds__(256) void gemm_bt(const u16* __restrict__ A,
                                               const u16* __restrict__ BT,
                                               int N, int mode,
                                               float* __restrict__ out0,
                                               u16* __restrict__ qb,
                                               float* __restrict__ kf,
                                               u16* __restrict__ kb,
                                               float* __restrict__ vf) {
  __shared__ u16 As[128 * 64];
  __shared__ u16 Bs[128 * 64];
  const int m0 = blockIdx.y * 128, n0 = blockIdx.x * 128;
  const int tid = threadIdx.x, lane = tid & 63, wave = tid >> 6;
  const int wm = wave & 1, wn = wave >> 1;
  const int c = lane & 15, quad = lane >> 4;
  const int srow = lane >> 3;                 // 0..7 row within 8-row chunk
  const int scol = (lane & 7) ^ (srow & 7);   // inverse-swizzled 16B column
  const int rkey = (c & 7) << 3;              // read-side XOR key (u16 units)

  f32x4 acc[4][4] = {};

  for (int k0 = 0; k0 < 1024; k0 += 64) {
    __syncthreads();   // previous compute done before overwriting tiles
#pragma unroll
    for (int it = 0; it < 4; it++) {
      int chunk = it * 4 + wave;              // 16 chunks of 8 rows x 128B
      int row = chunk * 8 + srow;
      GLOAD16(A + (size_t)(m0 + row) * 1024 + k0 + scol * 8, &As[chunk * 512]);
      GLOAD16(BT + (size_t)(n0 + row) * 1024 + k0 + scol * 8, &Bs[chunk * 512]);
    }
    __syncthreads();   // vmcnt drained at barrier -> tiles ready
#pragma unroll
    for (int kc = 0; kc < 64; kc += 32) {
      s16x8 af[4], bf[4];
#pragma unroll
      for (int i = 0; i < 4; i++) {
        af[i] = *(const s16x8*)&As[(((wm * 64 + i * 16 + c) << 6) + kc + quad * 8) ^ rkey];
        bf[i] = *(const s16x8*)&Bs[(((wn * 64 + i * 16 + c) << 6) + kc + quad * 8) ^ rkey];
      }
#pragma unroll
      for (int mi = 0; mi < 4; mi++)
#pragma unroll
        for (int ni = 0; ni < 4; ni++)
          acc[mi][ni] = __builtin_amdgcn_mfma_f32_16x16x32_bf16(af[mi], bf[ni], acc[mi][ni], 0, 0, 0);
    }
  }

  // epilogue: C[row = m0+wm*64+mi*16+quad*4+reg][col = n0+wn*64+ni*16+c]
#pragma unroll
  for (int mi = 0; mi < 4; mi++) {
#pragma unroll
    for (int ni = 0; ni < 4; ni++) {
      f32x4 v = acc[mi][ni];
      int gmb = m0 + wm * 64 + mi * 16 + quad * 4;
      int gn = n0 + wn * 64 + ni * 16 + c;
      if (mode == 0) {
#pragma unroll
        for (int r = 0; r < 4; r++)
          out0[(size_t)(gmb + r) * N + gn] = v[r];
      } else {
        int region = n0 >> 10;  // whole block-column lies in one region
        if (region == 0) {
#pragma unroll
          for (int r = 0; r < 4; r++)
            qb[(size_t)(gmb + r) * 1024 + gn] = f2bf(v[r] * QSCALE);
        } else if (region == 1) {
          int ccol = gn - 1024;
#pragma unroll
          for (int r = 0; r < 4; r++) {
            int gm = gmb + r, b = gm >> 11, t = gm & 2047;
            size_t off = (size_t)b * (SS * CC) + (size_t)(PP + t) * CC + ccol;
            kf[off] = v[r];
            kb[off] = f2bf(v[r]);
          }
        } else {
          int ccol = gn - 2048;
#pragma unroll
          for (int r = 0; r < 4; r++) {
            int gm = gmb + r, b = gm >> 11, t = gm & 2047;
            vf[(size_t)b * (SS * CC) + (size_t)(PP + t) * CC + ccol] = v[r];
          }
        }
      }
    }
  }
}

// ---------------- flash attention v10 ----------------
// v8 skeleton (8 waves x 16 q-rows, dbuf 1 barrier/iter, reg ones, rare-max branch,
// p2bf, setprio, XCD-pinned grid) with:
//  - K/V staged via global_load_lds (1 chunk each per wave) into LINEAR [64][64] buffers,
//    source-swizzled + XOR-read (rule-21 T2): no ds_writes, no staging VGPRs, DMA drains
//    at the single per-iter barrier.
//  - Ps[16][64] + XOR swizzle: conflict-free writes, uniform reads, LDS 48KB total.
__global__ __launch_bounds__(512, 4) void attn_kernel(const u16* __restrict__ qb,
                                                      const u16* __restrict__ kb,
                                                      const u16* __restrict__ vT,
                                                      u16* __restrict__ yb) {
  __shared__ u16 Ks[2][64 * 64];
  __shared__ u16 Vs[2][64 * 64];
  __shared__ u16 Ps[8][16 * 64];
  // XCD-pinned mapping (r3-verified bijection): XCD x owns bh 4x..4x+3; heavy q-tiles first
  const int L = blockIdx.x;
  const int xcd = L & 7, rest = L >> 3;
  const int qt = 15 - (rest >> 2);
  const int bh = (xcd << 2) | (rest & 3);
  const int b = bh >> 4, h = bh & 15;
  const int q0 = qt * 128;
  const int tid = threadIdx.x, lane = tid & 63, wave = tid >> 6;
  const int c = lane & 15, quad = lane >> 4;
  const int srow = lane >> 3;                 // 0..7 row within this wave's 8-row chunk
  const int scol = (lane & 7) ^ (srow & 7);   // inverse-swizzled 16B column
  const int rkey = (c & 7) << 3;              // read XOR key for K/V (u16 units)

  const int s_end = PP + q0 + 128;

  // DMA source bases: wave stages K rows s0+wave*8+srow, V rows d=wave*8+srow
  const u16* kg = kb + (size_t)(b * SS + wave * 8 + srow) * 1024 + h * 64 + scol * 8;
  const u16* vg = vT + ((size_t)bh * 64 + wave * 8 + srow) * SS + scol * 8;

  // prologue: tile 0 -> buffer 0 (DMA completes at first in-loop barrier)
  GLOAD16(kg, &Ks[0][wave * 512]);
  GLOAD16(vg, &Vs[0][wave * 512]);

  // ones B-operand in registers: B[k][n=c] = 1 iff c==0 (row-sum column)
  const short ov = (c == 0) ? (short)0x3F80 : (short)0;
  const s16x8 ones = { ov, ov, ov, ov, ov, ov, ov, ov };

  // Q fragments (A-layout): wave owns rows q0 + wave*16 + (0..15)
  s16x8 qf[2];
  {
    int qr = q0 + wave * 16 + c;
    qf[0] = *(const s16x8*)(qb + (size_t)(b * TT + qr) * 1024 + h * 64 + quad * 8);
    qf[1] = *(const s16x8*)(qb + (size_t)(b * TT + qr) * 1024 + h * 64 + 32 + quad * 8);
  }

  f32x4 o[5] = {};   // [0..3] output d-tiles, [4] row-sum (ones column)
  float m = -1e30f;
  u16* Pw = Ps[wave];

  int cur = 0;
  for (int s0 = 0; s0 < s_end; s0 += 64, cur ^= 1) {
    __syncthreads();   // drains DMA (tile cur ready); all waves done reading cur^1

    if (s0 + 64 < s_end) {   // issue next-tile DMA into the dead buffer
      GLOAD16(kg + (size_t)(s0 + 64) * 1024, &Ks[cur ^ 1][wave * 512]);
      GLOAD16(vg + (s0 + 64), &Vs[cur ^ 1][wave * 512]);
    }

    const u16* Kc = Ks[cur];
    const u16* Vc = Vs[cur];

    // scores (swizzled K reads)
    f32x4 sc[4];
    __builtin_amdgcn_s_setprio(1);
#pragma unroll
    for (int nt = 0; nt < 4; nt++) {
      s16x8 kf0 = *(const s16x8*)&Kc[(((nt * 16 + c) << 6) + quad * 8) ^ rkey];
      s16x8 kf1 = *(const s16x8*)&Kc[(((nt * 16 + c) << 6) + 32 + quad * 8) ^ rkey];
      f32x4 z = { 0.f, 0.f, 0.f, 0.f };
      z = __builtin_amdgcn_mfma_f32_16x16x32_bf16(qf[0], kf0, z, 0, 0, 0);
      z = __builtin_amdgcn_mfma_f32_16x16x32_bf16(qf[1], kf1, z, 0, 0, 0);
      sc[nt] = z;
    }
    __builtin_amdgcn_s_setprio(0);

    // V-frags hoisted (swizzled): LDS latency hides under mask/softmax VALU below
    s16x8 vf0[4], vf1[4];
#pragma unroll
    for (int dt = 0; dt < 4; dt++) {
      vf0[dt] = *(const s16x8*)&Vc[(((dt * 16 + c) << 6) + quad * 8) ^ rkey];
      vf1[dt] = *(const s16x8*)&Vc[(((dt * 16 + c) << 6) + 32 + quad * 8) ^ rkey];
    }

    const int diag = s0 - (PP + q0);
    if (diag >= 0) {  // causal mask (block diagonal region spans 2 tiles)
#pragma unroll
      for (int nt = 0; nt < 4; nt++) {
        int col = nt * 16 + c + diag;
#pragma unroll
        for (int r = 0; r < 4; r++) {
          int rq = wave * 16 + quad * 4 + r;
          if (col > rq) sc[nt][r] = -1e30f;
        }
      }
    }

    // defer-max: shuffle-free common path (wave max > m+8 <=> some lane's lm > m+8)
    float lm = -1e30f;
#pragma unroll
    for (int nt = 0; nt < 4; nt++)
      lm = fmaxf(lm, fmaxf(fmaxf(sc[nt][0], sc[nt][1]),
                           fmaxf(sc[nt][2], sc[nt][3])));
    if (__any(lm > m + 8.0f)) {            // rare (~once per block)
#pragma unroll
      for (int off = 1; off < 64; off <<= 1)
        lm = fmaxf(lm, __shfl_xor(lm, off, 64));
      float alpha = __builtin_amdgcn_exp2f(m - lm);
      m = lm;
#pragma unroll
      for (int dt = 0; dt < 5; dt++)
#pragma unroll
        for (int r = 0; r < 4; r++) o[dt][r] *= alpha;
    }

    // p = exp2(sc - m) -> bf16 -> Ps[16][64] XOR-swizzled (write ^quad<<4, read ^(c>>2)<<4)
    // write banks: ((nt*8 + c/2) ^ quad*8) -> 32 distinct = conflict-free
#pragma unroll
    for (int nt = 0; nt < 4; nt++)
#pragma unroll
      for (int r = 0; r < 4; r++)
        Pw[(((quad * 4 + r) << 6) + nt * 16 + c) ^ (quad << 4)] =
            p2bf(__builtin_amdgcn_exp2f(sc[nt][r] - m));
    const int pkey = (c >> 2) << 4;
    s16x8 pa0 = *(const s16x8*)&Pw[((c << 6) + quad * 8) ^ pkey];
    s16x8 pa1 = *(const s16x8*)&Pw[((c << 6) + 32 + quad * 8) ^ pkey];

    __builtin_amdgcn_s_setprio(1);
#pragma unroll
    for (int dt = 0; dt < 4; dt++) {
      o[dt] = __builtin_amdgcn_mfma_f32_16x16x32_bf16(pa0, vf0[dt], o[dt], 0, 0, 0);
      o[dt] = __builtin_amdgcn_mfma_f32_16x16x32_bf16(pa1, vf1[dt], o[dt], 0, 0, 0);
    }
    o[4] = __builtin_amdgcn_mfma_f32_16x16x32_bf16(pa0, ones, o[4], 0, 0, 0);
    o[4] = __builtin_amdgcn_mfma_f32_16x16x32_bf16(pa1, ones, o[4], 0, 0, 0);
    __builtin_amdgcn_s_setprio(0);
  }

  // normalize: l for q-row (quad*4+r) lives in o[4][r] at lane c==0 of each quad
#pragma unroll
  for (int r = 0; r < 4; r++) {
    float l = __shfl(o[4][r], (lane & 48), 64);
    float inv = 1.0f / l;
    int qr = q0 + wave * 16 + quad * 4 + r;
#pragma unroll
    for (int dt = 0; dt < 4; dt++)
      yb[(size_t)(b * TT + qr) * 1024 + h * 64 + dt * 16 + c] = f2bf(o[dt][r] * inv);
  }
}

extern "C" void kernel_launch(void* const* d_in, const int* in_sizes, int n_in,
                              void* d_out, int out_size, void* d_ws, size_t ws_size,
                              hipStream_t stream) {
  const float* x       = (const float*)d_in[0];
  const float* k_cache = (const float*)d_in[1];
  const float* v_cache = (const float*)d_in[2];
  const float* W_attn  = (const float*)d_in[3];
  const float* W_proj  = (const float*)d_in[4];

  float* out_y = (float*)d_out;                       // [B,T,C]   4,194,304
  float* out_k = out_y + (size_t)BB * TT * CC;        // [B,S,C]   8,388,608
  float* out_v = out_k + (size_t)BB * SS * CC;        // [B,S,C]   8,388,608

  u16* xb  = (u16*)d_ws;                 // 4,194,304  x bf16
  u16* WaT = xb  + 4194304;              // 3,145,728  W_attn^T bf16 [3072,1024]
  u16* WpT = WaT + 3145728;              // 1,048,576  W_proj^T bf16 [1024,1024]
  u16* qb  = WpT + 1048576;              // 4,194,304  q bf16 (scaled) [B*T,1024]
  u16* kb  = qb  + 4194304;              // 8,388,608  k bf16 [B,S,C]
  u16* vT  = kb  + 8388608;              // 8,388,608  v^T bf16 [B,H,64,S]
  u16* yb  = vT  + 8388608;              // 4,194,304  attn out bf16 [B*T,1024]

  cvt_f32_bf16<<<dim3(4096), dim3(256), 0, stream>>>(x, xb);
  transpose_w_bf16<<<dim3(48, 16), dim3(256), 0, stream>>>(W_attn, WaT, 1024, 3072);
  transpose_w_bf16<<<dim3(16, 16), dim3(256), 0, stream>>>(W_proj, WpT, 1024, 1024);
  cache_copy<<<dim3(4096), dim3(256), 0, stream>>>(k_cache, v_cache, out_k, out_v, kb);
  vT_cache_kernel<<<dim3(32, 32), dim3(256), 0, stream>>>(v_cache, vT);
  gemm_bt<<<dim3(24, 32), dim3(256), 0, stream>>>(xb, WaT, 3072, 1, nullptr, qb, out_k, kb, out_v);
  vT_rem_kernel<<<dim3(32, 32), dim3(256), 0, stream>>>(out_v, vT);
  attn_kernel<<<dim3(512), dim3(512), 0, stream>>>(qb, kb, vT, yb);
  gemm_bt<<<dim3(8, 32), dim3(256), 0, stream>>>(yb, WpT, 1024, 0, out_y, nullptr, nullptr, nullptr, nullptr);
}

// Round 8
// 305.938 us; speedup vs baseline: 1.2006x; 1.0353x over previous
//
#include <hip/hip_runtime.h>

// Problem constants: B=2, T=2048, P=2048, C=1024, H=16, HD=64, S=P+T=4096
#define BB 2
#define TT 2048
#define PP 2048
#define CC 1024
#define HH 16
#define SS 4096

typedef unsigned short u16;
typedef unsigned int u32;
typedef __attribute__((ext_vector_type(8))) short s16x8;
typedef __attribute__((ext_vector_type(4))) float f32x4;
typedef __attribute__((ext_vector_type(4))) unsigned short u16x4;

// async global->LDS DMA, 16B per lane: LDS dest = uniform base + lane*16
#define GLOAD16(g, l)                                                                   \
  __builtin_amdgcn_global_load_lds((const __attribute__((address_space(1))) u32*)(g),   \
                                   (__attribute__((address_space(3))) u32*)(l), 16, 0, 0)

// fold 1/sqrt(HD)=0.125 and log2(e) into q so softmax uses exp2 directly
#define QSCALE 0.18033688011112042f

__device__ __forceinline__ u16 f2bf(float f) {
  unsigned u = __float_as_uint(f);
  u += 0x7fff + ((u >> 16) & 1);   // RNE
  return (u16)(u >> 16);
}

// cheap round-half-up bf16 for P (positive values; ties-vs-RNE diff << threshold headroom)
__device__ __forceinline__ u16 p2bf(float f) {
  return (u16)((__float_as_uint(f) + 0x8000u) >> 16);
}

// ---------------- elementwise fp32 -> bf16 (x) ----------------
__global__ __launch_bounds__(256) void cvt_f32_bf16(const float* __restrict__ src,
                                                    u16* __restrict__ dst) {
  size_t i = ((size_t)blockIdx.x * 256 + threadIdx.x) * 4;
  f32x4 v = *(const f32x4*)(src + i);
  u16x4 o = { f2bf(v[0]), f2bf(v[1]), f2bf(v[2]), f2bf(v[3]) };
  *(u16x4*)(dst + i) = o;
}

// ---------------- transpose + convert: dst[c][r] = bf16(src[r][c]) ----------------
__global__ __launch_bounds__(256) void transpose_w_bf16(const float* __restrict__ src,
                                                        u16* __restrict__ dst,
                                                        int rows, int cols) {
  __shared__ float tile[64][65];
  int r0 = blockIdx.y * 64, c0 = blockIdx.x * 64;
  int tx = threadIdx.x & 63, ty = threadIdx.x >> 6;
#pragma unroll
  for (int i = 0; i < 16; i++) {
    int r = ty + i * 4;
    tile[r][tx] = src[(size_t)(r0 + r) * cols + c0 + tx];
  }
  __syncthreads();
#pragma unroll
  for (int i = 0; i < 16; i++) {
    int cc = ty + i * 4;
    dst[(size_t)(c0 + cc) * rows + r0 + tx] = f2bf(tile[tx][cc]);
  }
}

// ---------------- fused cache prep: kc/vc read ONCE ----------------
// writes kf, vf (fp32 passthrough with T-row gap), kb (bf16), and vT (transposed bf16 V)
__global__ __launch_bounds__(256) void cache_prep(const float* __restrict__ kc,
                                                  const float* __restrict__ vc,
                                                  float* __restrict__ kf,
                                                  float* __restrict__ vf,
                                                  u16* __restrict__ kb,
                                                  u16* __restrict__ vTb) {
  __shared__ float tile[64][65];
  int bh = blockIdx.y, b = bh >> 4, h = bh & 15;
  int p0 = blockIdx.x * 64;
  int tx = threadIdx.x & 63, ty = threadIdx.x >> 6;
#pragma unroll
  for (int i = 0; i < 16; i++) {
    int p = ty + i * 4;
    size_t src = (size_t)(b * PP + p0 + p) * CC + h * 64 + tx;
    size_t dst = (size_t)(b * SS + p0 + p) * CC + h * 64 + tx;
    float kv = kc[src];
    float vv = vc[src];
    kf[dst] = kv;
    vf[dst] = vv;
    kb[dst] = f2bf(kv);
    tile[p][tx] = vv;
  }
  __syncthreads();
#pragma unroll
  for (int i = 0; i < 16; i++) {
    int d = ty + i * 4;
    vTb[(size_t)((b * HH + h) * 64 + d) * SS + p0 + tx] = f2bf(tile[tx][d]);
  }
}

// ---------------- v_rem (fp32 rows PP.. of out_v) -> vT bf16 ----------------
__global__ __launch_bounds__(256) void vT_rem_kernel(const float* __restrict__ vf,
                                                     u16* __restrict__ vTb) {
  __shared__ float tile[64][65];
  int bh = blockIdx.y, b = bh >> 4, h = bh & 15;
  int p0 = blockIdx.x * 64;  // within T
  int tx = threadIdx.x & 63, ty = threadIdx.x >> 6;
#pragma unroll
  for (int i = 0; i < 16; i++) {
    int p = ty + i * 4;
    tile[p][tx] = vf[(size_t)(b * SS + PP + p0 + p) * CC + h * 64 + tx];
  }
  __syncthreads();
#pragma unroll
  for (int i = 0; i < 16; i++) {
    int d = ty + i * 4;
    vTb[(size_t)((b * HH + h) * 64 + d) * SS + PP + p0 + tx] = f2bf(tile[tx][d]);
  }
}

// ---------------- GEMM: C[MxN] = A[Mx1024] * BT[Nx1024]^T (bf16 MFMA) ----------------
// m97-style staging: global_load_lds width-16 into LINEAR [128][64] LDS, source-swizzled
// (scol = (lane&7)^(srow&7)) so reads XOR (row&7)<<3 are bank-uniform (rule-21 T2).
// mode 1: qkv routing epilogue (used for the QKV GEMM).
__global__ __launch_bounds__(256) void gemm_bt(const u16* __restrict__ A,
                                               const u16* __restrict__ BT,
                                               int N, int mode,
                                               float* __restrict__ out0,
                                               u16* __restrict__ qb,
                                               float* __restrict__ kf,
                                               u16* __restrict__ kb,
                                               float* __restrict__ vf) {
  __shared__ u16 As[128 * 64];
  __shared__ u16 Bs[128 * 64];
  const int m0 = blockIdx.y * 128, n0 = blockIdx.x * 128;
  const int tid = threadIdx.x, lane = tid & 63, wave = tid >> 6;
  const int wm = wave & 1, wn = wave >> 1;
  const int c = lane & 15, quad = lane >> 4;
  const int srow = lane >> 3;                 // 0..7 row within 8-row chunk
  const int scol = (lane & 7) ^ (srow & 7);   // inverse-swizzled 16B column
  const int rkey = (c & 7) << 3;              // read-side XOR key (u16 units)

  f32x4 acc[4][4] = {};

  for (int k0 = 0; k0 < 1024; k0 += 64) {
    __syncthreads();   // previous compute done before overwriting tiles
#pragma unroll
    for (int it = 0; it < 4; it++) {
      int chunk = it * 4 + wave;              // 16 chunks of 8 rows x 128B
      int row = chunk * 8 + srow;
      GLOAD16(A + (size_t)(m0 + row) * 1024 + k0 + scol * 8, &As[chunk * 512]);
      GLOAD16(BT + (size_t)(n0 + row) * 1024 + k0 + scol * 8, &Bs[chunk * 512]);
    }
    __syncthreads();   // vmcnt drained at barrier -> tiles ready
#pragma unroll
    for (int kc = 0; kc < 64; kc += 32) {
      s16x8 af[4], bf[4];
#pragma unroll
      for (int i = 0; i < 4; i++) {
        af[i] = *(const s16x8*)&As[(((wm * 64 + i * 16 + c) << 6) + kc + quad * 8) ^ rkey];
        bf[i] = *(const s16x8*)&Bs[(((wn * 64 + i * 16 + c) << 6) + kc + quad * 8) ^ rkey];
      }
#pragma unroll
      for (int mi = 0; mi < 4; mi++)
#pragma unroll
        for (int ni = 0; ni < 4; ni++)
          acc[mi][ni] = __builtin_amdgcn_mfma_f32_16x16x32_bf16(af[mi], bf[ni], acc[mi][ni], 0, 0, 0);
    }
  }

  // epilogue: C[row = m0+wm*64+mi*16+quad*4+reg][col = n0+wn*64+ni*16+c]
#pragma unroll
  for (int mi = 0; mi < 4; mi++) {
#pragma unroll
    for (int ni = 0; ni < 4; ni++) {
      f32x4 v = acc[mi][ni];
      int gmb = m0 + wm * 64 + mi * 16 + quad * 4;
      int gn = n0 + wn * 64 + ni * 16 + c;
      if (mode == 0) {
#pragma unroll
        for (int r = 0; r < 4; r++)
          out0[(size_t)(gmb + r) * N + gn] = v[r];
      } else {
        int region = n0 >> 10;  // whole block-column lies in one region
        if (region == 0) {
#pragma unroll
          for (int r = 0; r < 4; r++)
            qb[(size_t)(gmb + r) * 1024 + gn] = f2bf(v[r] * QSCALE);
        } else if (region == 1) {
          int ccol = gn - 1024;
#pragma unroll
          for (int r = 0; r < 4; r++) {
            int gm = gmb + r, b = gm >> 11, t = gm & 2047;
            size_t off = (size_t)b * (SS * CC) + (size_t)(PP + t) * CC + ccol;
            kf[off] = v[r];
            kb[off] = f2bf(v[r]);
          }
        } else {
          int ccol = gn - 2048;
#pragma unroll
          for (int r = 0; r < 4; r++) {
            int gm = gmb + r, b = gm >> 11, t = gm & 2047;
            vf[(size_t)b * (SS * CC) + (size_t)(PP + t) * CC + ccol] = v[r];
          }
        }
      }
    }
  }
}

// ---------------- proj GEMM: 64x128 tile, grid (N/128, M/64) = 512 blocks = 2/CU ----------------
__global__ __launch_bounds__(256) void gemm_bt64(const u16* __restrict__ A,
                                                 const u16* __restrict__ BT,
                                                 float* __restrict__ out0) {
  __shared__ u16 As[64 * 64];
  __shared__ u16 Bs[128 * 64];
  const int m0 = blockIdx.y * 64, n0 = blockIdx.x * 128;
  const int tid = threadIdx.x, lane = tid & 63, wave = tid >> 6;
  const int wm = wave & 1, wn = wave >> 1;
  const int c = lane & 15, quad = lane >> 4;
  const int srow = lane >> 3;
  const int scol = (lane & 7) ^ (srow & 7);
  const int rkey = (c & 7) << 3;

  f32x4 acc[2][4] = {};

  for (int k0 = 0; k0 < 1024; k0 += 64) {
    __syncthreads();
#pragma unroll
    for (int it = 0; it < 6; it++) {
      int idx = it * 4 + wave;     // 0..23: 8 A-chunks then 16 B-chunks (8 rows x 128B each)
      if (idx < 8)
        GLOAD16(A + (size_t)(m0 + idx * 8 + srow) * 1024 + k0 + scol * 8, &As[idx * 512]);
      else
        GLOAD16(BT + (size_t)(n0 + (idx - 8) * 8 + srow) * 1024 + k0 + scol * 8,
                &Bs[(idx - 8) * 512]);
    }
    __syncthreads();
#pragma unroll
    for (int kc = 0; kc < 64; kc += 32) {
      s16x8 af[2], bf[4];
#pragma unroll
      for (int i = 0; i < 2; i++)
        af[i] = *(const s16x8*)&As[(((wm * 32 + i * 16 + c) << 6) + kc + quad * 8) ^ rkey];
#pragma unroll
      for (int i = 0; i < 4; i++)
        bf[i] = *(const s16x8*)&Bs[(((wn * 64 + i * 16 + c) << 6) + kc + quad * 8) ^ rkey];
#pragma unroll
      for (int mi = 0; mi < 2; mi++)
#pragma unroll
        for (int ni = 0; ni < 4; ni++)
          acc[mi][ni] = __builtin_amdgcn_mfma_f32_16x16x32_bf16(af[mi], bf[ni], acc[mi][ni], 0, 0, 0);
    }
  }

#pragma unroll
  for (int mi = 0; mi < 2; mi++) {
#pragma unroll
    for (int ni = 0; ni < 4; ni++) {
      f32x4 v = acc[mi][ni];
      int gmb = m0 + wm * 32 + mi * 16 + quad * 4;
      int gn = n0 + wn * 64 + ni * 16 + c;
#pragma unroll
      for (int r = 0; r < 4; r++)
        out0[(size_t)(gmb + r) * 1024 + gn] = v[r];
    }
  }
}

// ---------------- flash attention v11: v10 + snake load-balance ----------------
// 8 waves x 16 q-rows, DMA-staged dbuf K/V (1 barrier/iter), swizzled reads, reg ones,
// rare-max branch, p2bf, setprio, XCD-pinned grid. Snake qt-pairing: blocks L and L+256
// (co-resident on one CU) now sum to a CONSTANT 98 iterations (was 84..112).
__global__ __launch_bounds__(512, 4) void attn_kernel(const u16* __restrict__ qb,
                                                      const u16* __restrict__ kb,
                                                      const u16* __restrict__ vT,
                                                      u16* __restrict__ yb) {
  __shared__ u16 Ks[2][64 * 64];
  __shared__ u16 Vs[2][64 * 64];
  __shared__ u16 Ps[8][16 * 64];
  const int L = blockIdx.x;
  const int xcd = L & 7, rest = L >> 3;
  const int h16 = rest >> 2;                  // 0..15 dispatch-order index
  const int qt = (h16 < 8) ? (15 - h16) : (h16 - 8);  // snake: pair sums constant
  const int bh = (xcd << 2) | (rest & 3);     // XCD x owns bh 4x..4x+3
  const int b = bh >> 4, h = bh & 15;
  const int q0 = qt * 128;
  const int tid = threadIdx.x, lane = tid & 63, wave = tid >> 6;
  const int c = lane & 15, quad = lane >> 4;
  const int srow = lane >> 3;                 // 0..7 row within this wave's 8-row chunk
  const int scol = (lane & 7) ^ (srow & 7);   // inverse-swizzled 16B column
  const int rkey = (c & 7) << 3;              // read XOR key for K/V (u16 units)

  const int s_end = PP + q0 + 128;

  // DMA source bases: wave stages K rows s0+wave*8+srow, V rows d=wave*8+srow
  const u16* kg = kb + (size_t)(b * SS + wave * 8 + srow) * 1024 + h * 64 + scol * 8;
  const u16* vg = vT + ((size_t)bh * 64 + wave * 8 + srow) * SS + scol * 8;

  // prologue: tile 0 -> buffer 0 (DMA completes at first in-loop barrier)
  GLOAD16(kg, &Ks[0][wave * 512]);
  GLOAD16(vg, &Vs[0][wave * 512]);

  // ones B-operand in registers: B[k][n=c] = 1 iff c==0 (row-sum column)
  const short ov = (c == 0) ? (short)0x3F80 : (short)0;
  const s16x8 ones = { ov, ov, ov, ov, ov, ov, ov, ov };

  // Q fragments (A-layout): wave owns rows q0 + wave*16 + (0..15)
  s16x8 qf[2];
  {
    int qr = q0 + wave * 16 + c;
    qf[0] = *(const s16x8*)(qb + (size_t)(b * TT + qr) * 1024 + h * 64 + quad * 8);
    qf[1] = *(const s16x8*)(qb + (size_t)(b * TT + qr) * 1024 + h * 64 + 32 + quad * 8);
  }

  f32x4 o[5] = {};   // [0..3] output d-tiles, [4] row-sum (ones column)
  float m = -1e30f;
  u16* Pw = Ps[wave];

  int cur = 0;
  for (int s0 = 0; s0 < s_end; s0 += 64, cur ^= 1) {
    __syncthreads();   // drains DMA (tile cur ready); all waves done reading cur^1

    if (s0 + 64 < s_end) {   // issue next-tile DMA into the dead buffer
      GLOAD16(kg + (size_t)(s0 + 64) * 1024, &Ks[cur ^ 1][wave * 512]);
      GLOAD16(vg + (s0 + 64), &Vs[cur ^ 1][wave * 512]);
    }

    const u16* Kc = Ks[cur];
    const u16* Vc = Vs[cur];

    // scores (swizzled K reads)
    f32x4 sc[4];
    __builtin_amdgcn_s_setprio(1);
#pragma unroll
    for (int nt = 0; nt < 4; nt++) {
      s16x8 kf0 = *(const s16x8*)&Kc[(((nt * 16 + c) << 6) + quad * 8) ^ rkey];
      s16x8 kf1 = *(const s16x8*)&Kc[(((nt * 16 + c) << 6) + 32 + quad * 8) ^ rkey];
      f32x4 z = { 0.f, 0.f, 0.f, 0.f };
      z = __builtin_amdgcn_mfma_f32_16x16x32_bf16(qf[0], kf0, z, 0, 0, 0);
      z = __builtin_amdgcn_mfma_f32_16x16x32_bf16(qf[1], kf1, z, 0, 0, 0);
      sc[nt] = z;
    }
    __builtin_amdgcn_s_setprio(0);

    // V-frags hoisted (swizzled): LDS latency hides under mask/softmax VALU below
    s16x8 vf0[4], vf1[4];
#pragma unroll
    for (int dt = 0; dt < 4; dt++) {
      vf0[dt] = *(const s16x8*)&Vc[(((dt * 16 + c) << 6) + quad * 8) ^ rkey];
      vf1[dt] = *(const s16x8*)&Vc[(((dt * 16 + c) << 6) + 32 + quad * 8) ^ rkey];
    }

    const int diag = s0 - (PP + q0);
    if (diag >= 0) {  // causal mask (block diagonal region spans 2 tiles)
#pragma unroll
      for (int nt = 0; nt < 4; nt++) {
        int col = nt * 16 + c + diag;
#pragma unroll
        for (int r = 0; r < 4; r++) {
          int rq = wave * 16 + quad * 4 + r;
          if (col > rq) sc[nt][r] = -1e30f;
        }
      }
    }

    // defer-max: shuffle-free common path (wave max > m+8 <=> some lane's lm > m+8)
    float lm = -1e30f;
#pragma unroll
    for (int nt = 0; nt < 4; nt++)
      lm = fmaxf(lm, fmaxf(fmaxf(sc[nt][0], sc[nt][1]),
                           fmaxf(sc[nt][2], sc[nt][3])));
    if (__any(lm > m + 8.0f)) {            // rare (~once per block)
#pragma unroll
      for (int off = 1; off < 64; off <<= 1)
        lm = fmaxf(lm, __shfl_xor(lm, off, 64));
      float alpha = __builtin_amdgcn_exp2f(m - lm);
      m = lm;
#pragma unroll
      for (int dt = 0; dt < 5; dt++)
#pragma unroll
        for (int r = 0; r < 4; r++) o[dt][r] *= alpha;
    }

    // p = exp2(sc - m) -> bf16 -> Ps[16][64] XOR-swizzled (write ^quad<<4, read ^(c>>2)<<4)
#pragma unroll
    for (int nt = 0; nt < 4; nt++)
#pragma unroll
      for (int r = 0; r < 4; r++)
        Pw[(((quad * 4 + r) << 6) + nt * 16 + c) ^ (quad << 4)] =
            p2bf(__builtin_amdgcn_exp2f(sc[nt][r] - m));
    const int pkey = (c >> 2) << 4;
    s16x8 pa0 = *(const s16x8*)&Pw[((c << 6) + quad * 8) ^ pkey];
    s16x8 pa1 = *(const s16x8*)&Pw[((c << 6) + 32 + quad * 8) ^ pkey];

    __builtin_amdgcn_s_setprio(1);
#pragma unroll
    for (int dt = 0; dt < 4; dt++) {
      o[dt] = __builtin_amdgcn_mfma_f32_16x16x32_bf16(pa0, vf0[dt], o[dt], 0, 0, 0);
      o[dt] = __builtin_amdgcn_mfma_f32_16x16x32_bf16(pa1, vf1[dt], o[dt], 0, 0, 0);
    }
    o[4] = __builtin_amdgcn_mfma_f32_16x16x32_bf16(pa0, ones, o[4], 0, 0, 0);
    o[4] = __builtin_amdgcn_mfma_f32_16x16x32_bf16(pa1, ones, o[4], 0, 0, 0);
    __builtin_amdgcn_s_setprio(0);
  }

  // normalize: l for q-row (quad*4+r) lives in o[4][r] at lane c==0 of each quad
#pragma unroll
  for (int r = 0; r < 4; r++) {
    float l = __shfl(o[4][r], (lane & 48), 64);
    float inv = 1.0f / l;
    int qr = q0 + wave * 16 + quad * 4 + r;
#pragma unroll
    for (int dt = 0; dt < 4; dt++)
      yb[(size_t)(b * TT + qr) * 1024 + h * 64 + dt * 16 + c] = f2bf(o[dt][r] * inv);
  }
}

extern "C" void kernel_launch(void* const* d_in, const int* in_sizes, int n_in,
                              void* d_out, int out_size, void* d_ws, size_t ws_size,
                              hipStream_t stream) {
  const float* x       = (const float*)d_in[0];
  const float* k_cache = (const float*)d_in[1];
  const float* v_cache = (const float*)d_in[2];
  const float* W_attn  = (const float*)d_in[3];
  const float* W_proj  = (const float*)d_in[4];

  float* out_y = (float*)d_out;                       // [B,T,C]   4,194,304
  float* out_k = out_y + (size_t)BB * TT * CC;        // [B,S,C]   8,388,608
  float* out_v = out_k + (size_t)BB * SS * CC;        // [B,S,C]   8,388,608

  u16* xb  = (u16*)d_ws;                 // 4,194,304  x bf16
  u16* WaT = xb  + 4194304;              // 3,145,728  W_attn^T bf16 [3072,1024]
  u16* WpT = WaT + 3145728;              // 1,048,576  W_proj^T bf16 [1024,1024]
  u16* qb  = WpT + 1048576;              // 4,194,304  q bf16 (scaled) [B*T,1024]
  u16* kb  = qb  + 4194304;              // 8,388,608  k bf16 [B,S,C]
  u16* vT  = kb  + 8388608;              // 8,388,608  v^T bf16 [B,H,64,S]
  u16* yb  = vT  + 8388608;              // 4,194,304  attn out bf16 [B*T,1024]

  cvt_f32_bf16<<<dim3(4096), dim3(256), 0, stream>>>(x, xb);
  transpose_w_bf16<<<dim3(48, 16), dim3(256), 0, stream>>>(W_attn, WaT, 1024, 3072);
  transpose_w_bf16<<<dim3(16, 16), dim3(256), 0, stream>>>(W_proj, WpT, 1024, 1024);
  cache_prep<<<dim3(32, 32), dim3(256), 0, stream>>>(k_cache, v_cache, out_k, out_v, kb, vT);
  gemm_bt<<<dim3(24, 32), dim3(256), 0, stream>>>(xb, WaT, 3072, 1, nullptr, qb, out_k, kb, out_v);
  vT_rem_kernel<<<dim3(32, 32), dim3(256), 0, stream>>>(out_v, vT);
  attn_kernel<<<dim3(512), dim3(512), 0, stream>>>(qb, kb, vT, yb);
  gemm_bt64<<<dim3(8, 64), dim3(256), 0, stream>>>(yb, WpT, out_y);
}